// Round 2
// baseline (321.657 us; speedup 1.0000x reference)
//
#include <hip/hip_runtime.h>
#include <hip/hip_bf16.h>

// HQQ 4-bit linear: out = x @ dequant(W_q)^T + bias
// M=B*S=4096, K=4096, N=4096, GROUP=128. Output FP32.
//
// Round 8: replace the 128x128 / 2-barrier GEMM (1057 TF, MfmaUtil 51%) with a
// 256x256-tile, ring-4 K-pipelined GEMM using counted vmcnt (T4), raw
// s_barrier (no __syncthreads -> no compiler vmcnt(0) drain), setprio around
// the MFMA cluster (T5), XOR-swizzled LDS staged via pre-swizzled global
// source (T2, rule #21), and XCD-bijective block swizzle (T1).
//   - K tiles of 32, ring of 4 buffers/operand (128 KiB LDS, 1 block/CU).
//   - Iteration: barrier; stage tile kt+3 (4 global_load_lds); vmcnt(8);
//     barrier; 12 ds_read_b128 + 32 MFMA. Tiles kt+2,kt+3 stay in flight
//     across barriers; vmcnt never drains to 0 in the main loop.
// Prepass (fused x->bf16 + Wq dequant) unchanged from round 7.

typedef __bf16 bf16x8 __attribute__((ext_vector_type(8)));
typedef float f32x4 __attribute__((ext_vector_type(4)));

#define BM 128
#define BN 128
#define BK 64

static __device__ __forceinline__ int pack_bf16x2(float a, float b) {
    __hip_bfloat162 p = __float22bfloat162_rn(make_float2(a, b));
    int r;
    __builtin_memcpy(&r, &p, 4);
    return r;
}

// ---------------- fused pre-pass: convert x AND dequant Wq ------------------
__global__ __launch_bounds__(256) void prepass_kernel(
    const float* __restrict__ X, unsigned short* __restrict__ Ad,
    const int*   __restrict__ Wq,
    const float* __restrict__ scale,
    const float* __restrict__ zero,
    unsigned short* __restrict__ Wd,
    int aUnits, int wUnits, int K, int G, int GROUP)
{
    const int stride = gridDim.x * blockDim.x;
    const int t0     = blockIdx.x * blockDim.x + threadIdx.x;

    for (int u = t0; u < aUnits; u += stride) {
        const long long f = (long long)u * 8;
        const float4 a0 = *(const float4*)(X + f);
        const float4 a1 = *(const float4*)(X + f + 4);
        int4 d;
        d.x = pack_bf16x2(a0.x, a0.y);
        d.y = pack_bf16x2(a0.z, a0.w);
        d.z = pack_bf16x2(a1.x, a1.y);
        d.w = pack_bf16x2(a1.z, a1.w);
        *(int4*)(Ad + f) = d;
    }

    const int unitsPerRow = K >> 3;
    for (int u = t0; u < wUnits; u += stride) {
        const int n = u / unitsPerRow;
        const int k = (u - n * unitsPerRow) * 8;
        const int g = k / GROUP;
        const float s  = scale[(long long)n * G + g];
        const float z  = zero [(long long)n * G + g];
        const float mz = -z * s;

        const long long f = (long long)n * K + k;
        const int4 q0 = *(const int4*)(Wq + f);
        const int4 q1 = *(const int4*)(Wq + f + 4);
        int4 d;
        d.x = pack_bf16x2((float)q0.x * s + mz, (float)q0.y * s + mz);
        d.y = pack_bf16x2((float)q0.z * s + mz, (float)q0.w * s + mz);
        d.z = pack_bf16x2((float)q1.x * s + mz, (float)q1.y * s + mz);
        d.w = pack_bf16x2((float)q1.z * s + mz, (float)q1.w * s + mz);
        *(int4*)(Wd + f) = d;
    }
}

// ---------------- GEMM: 256x256 tile, ring-4 K-pipeline ---------------------
// C[M,N] = A[M,K] * Bw[N,K]^T + bias. 512 threads = 8 waves (2M x 4N); wave
// owns 128x64 of C = 8x4 fragments of 16x16. K tiles of KT=32.
//
// LDS per operand per tile: 256 logical rows x 32 k-cols bf16 = 16 KB stored
// as 128 physical rows x 128 B; phys row R packs logical rows 2R,2R+1 (4
// chunks of 8 bf16 each). Swizzle: phys slot j of row R holds logical
// (dr,c) with ju = j ^ (R&7), dr = ju>>2, c = ju&3. Writers (global_load_lds,
// linear LDS dest) fetch the pre-swizzled global chunk; readers XOR the same
// term -> involution. Read-side bank spread: 2 lanes/bank (free).
#define KT 32
#define NRING 4

__global__ __launch_bounds__(512, 2) void gemm256_bf16_nt(
    const unsigned short* __restrict__ A,     // bf16 bits [M,K]
    const unsigned short* __restrict__ Bw,    // bf16 bits [N,K]
    const float* __restrict__ bias,           // fp32 [N]
    float*       __restrict__ C,              // fp32 [M,N]
    int M, int N, int K)
{
    __shared__ unsigned short ldsA[NRING][128 * 64];   // 4 x 16 KB
    __shared__ unsigned short ldsB[NRING][128 * 64];   // 4 x 16 KB

    const int tid  = threadIdx.x;
    const int lane = tid & 63;
    const int wave = tid >> 6;     // 0..7
    const int wm   = wave >> 2;    // 0..1  (M half)
    const int wn   = wave & 3;     // 0..3  (N quarter)

    // XCD-bijective swizzle: nwg = (N/256)*(M/256), contiguous chunk per XCD.
    const int nwg  = (N >> 8) * (M >> 8);
    const int cpx  = nwg >> 3;                       // nwg % 8 == 0 guaranteed
    const int bid  = blockIdx.x;
    const int wgid = (bid & 7) * cpx + (bid >> 3);
    const int bx   = wgid % (N >> 8);
    const int by   = wgid / (N >> 8);
    const int blockN0 = bx << 8;
    const int blockM0 = by << 8;

    // ---- staging address precompute (loop-invariant) ----
    // load l in {0,1}: slot s = l*512 + tid; R = s>>3; j = s&7.
    // ju = j ^ (R&7); logical row r = 2R + (ju>>2); chunk c = ju&3.
    long long gOffA[2], gOffB[2];
    int ldsO[2];
#pragma unroll
    for (int l = 0; l < 2; ++l) {
        const int s  = l * 512 + tid;
        const int R  = s >> 3;
        const int j  = s & 7;
        const int ju = j ^ (R & 7);
        const int r  = 2 * R + (ju >> 2);
        const int c  = ju & 3;
        gOffA[l] = (long long)(blockM0 + r) * K + c * 8;
        gOffB[l] = (long long)(blockN0 + r) * K + c * 8;
        ldsO[l]  = (l * 512 + wave * 64) * 8;        // wave-uniform base (elems)
    }

    // ---- fragment read offsets (loop-invariant, elements) ----
    const int row16 = lane & 15;
    const int quad  = lane >> 4;
    int offA[8], offB[4];
#pragma unroll
    for (int m = 0; m < 8; ++m) {
        const int r = wm * 128 + m * 16 + row16;
        const int R = r >> 1;
        const int j = ((r & 1) * 4 + quad) ^ (R & 7);
        offA[m] = R * 64 + j * 8;
    }
#pragma unroll
    for (int n = 0; n < 4; ++n) {
        const int r = wn * 64 + n * 16 + row16;
        const int R = r >> 1;
        const int j = ((r & 1) * 4 + quad) ^ (R & 7);
        offB[n] = R * 64 + j * 8;
    }

    f32x4 acc[8][4];
#pragma unroll
    for (int m = 0; m < 8; ++m)
#pragma unroll
        for (int n = 0; n < 4; ++n)
            acc[m][n] = (f32x4){0.f, 0.f, 0.f, 0.f};

#define STAGE(kt_, ring_)                                                     \
    do {                                                                      \
        const long long kOff_ = (long long)(kt_) * KT;                        \
        _Pragma("unroll")                                                     \
        for (int l = 0; l < 2; ++l) {                                         \
            __builtin_amdgcn_global_load_lds(                                 \
                (const __attribute__((address_space(1))) unsigned int*)       \
                    (A + gOffA[l] + kOff_),                                   \
                (__attribute__((address_space(3))) unsigned int*)             \
                    (&ldsA[ring_][ldsO[l]]),                                  \
                16, 0, 0);                                                    \
        }                                                                     \
        _Pragma("unroll")                                                     \
        for (int l = 0; l < 2; ++l) {                                         \
            __builtin_amdgcn_global_load_lds(                                 \
                (const __attribute__((address_space(1))) unsigned int*)       \
                    (Bw + gOffB[l] + kOff_),                                  \
                (__attribute__((address_space(3))) unsigned int*)             \
                    (&ldsB[ring_][ldsO[l]]),                                  \
                16, 0, 0);                                                    \
        }                                                                     \
    } while (0)

#define COMPUTE(ring_)                                                        \
    do {                                                                      \
        bf16x8 av[8], bv[4];                                                  \
        _Pragma("unroll")                                                     \
        for (int n = 0; n < 4; ++n)                                           \
            bv[n] = *(const bf16x8*)&ldsB[ring_][offB[n]];                    \
        _Pragma("unroll")                                                     \
        for (int m = 0; m < 8; ++m)                                           \
            av[m] = *(const bf16x8*)&ldsA[ring_][offA[m]];                    \
        __builtin_amdgcn_s_setprio(1);                                        \
        _Pragma("unroll")                                                     \
        for (int m = 0; m < 8; ++m)                                           \
            _Pragma("unroll")                                                 \
            for (int n = 0; n < 4; ++n)                                       \
                acc[m][n] = __builtin_amdgcn_mfma_f32_16x16x32_bf16(          \
                    av[m], bv[n], acc[m][n], 0, 0, 0);                        \
        __builtin_amdgcn_s_setprio(0);                                        \
    } while (0)

    const int NT = K / KT;                  // 128 tiles

    // prologue: stage tiles 0,1,2 (12 loads in flight)
    STAGE(0, 0);
    STAGE(1, 1);
    STAGE(2, 2);

    // main loop: computes tiles 0..NT-4; stages kt+3; vmcnt(8) retires kt+1.
    // Tile kt was retired at iteration kt-1 -> ready. Raw barriers only.
    for (int kt = 0; kt < NT - 3; ++kt) {
        __builtin_amdgcn_s_barrier();       // prev compute's readers done
        STAGE(kt + 3, (kt + 3) & 3);
        asm volatile("s_waitcnt vmcnt(8)" ::: "memory");
        __builtin_amdgcn_s_barrier();       // tile kt visible to all waves
        COMPUTE(kt & 3);
    }

    // epilogue: drain and compute the last 3 tiles (buffers static now)
    __builtin_amdgcn_s_barrier();
    asm volatile("s_waitcnt vmcnt(0)" ::: "memory");
    __builtin_amdgcn_s_barrier();
    COMPUTE((NT - 3) & 3);
    COMPUTE((NT - 2) & 3);
    COMPUTE((NT - 1) & 3);

#undef STAGE
#undef COMPUTE

    // ---- C write: layout col=lane&15, row=quad*4+reg [m89-verified] ----
    const int colBase = blockN0 + wn * 64;
    const int rowBase = blockM0 + wm * 128;
    float biasf[4];
#pragma unroll
    for (int n = 0; n < 4; ++n)
        biasf[n] = bias[colBase + n * 16 + row16];

#pragma unroll
    for (int m = 0; m < 8; ++m) {
        const int row0 = rowBase + m * 16 + quad * 4;
#pragma unroll
        for (int n = 0; n < 4; ++n) {
            const int col = colBase + n * 16 + row16;
#pragma unroll
            for (int r = 0; r < 4; ++r) {
                C[(long long)(row0 + r) * N + col] = acc[m][n][r] + biasf[n];
            }
        }
    }
}

// ---------------- legacy 128x128 GEMM (fallback for odd shapes) -------------
__global__ __launch_bounds__(256, 2) void gemm_bf16_nt(
    const unsigned short* __restrict__ A,
    const unsigned short* __restrict__ Bw,
    const float* __restrict__ bias,
    float*       __restrict__ C,
    int M, int N, int K)
{
    __shared__ unsigned short ldsA[BM * BK];
    __shared__ unsigned short ldsB[BN * BK];

    const int tid   = threadIdx.x;
    const int lane  = tid & 63;
    const int wave  = tid >> 6;
    const int waveM = wave >> 1;
    const int waveN = wave & 1;

    const int blockN0 = blockIdx.x * BN;
    const int blockM0 = blockIdx.y * BM;

    const long long aBase = (long long)blockM0 * K;
    const long long bBase = (long long)blockN0 * K;

    const int rowInChunk = lane >> 3;
    const int colChunkSw = (lane & 7) ^ rowInChunk;
    const int col8       = colChunkSw * 8;

    f32x4 acc[4][4];
#pragma unroll
    for (int i = 0; i < 4; ++i)
#pragma unroll
        for (int j = 0; j < 4; ++j)
            acc[i][j] = (f32x4){0.f, 0.f, 0.f, 0.f};

    const int row16 = lane & 15;
    const int quad  = lane >> 4;
    const int sw    = row16 & 7;

    for (int k0 = 0; k0 < K; k0 += BK) {
        __syncthreads();
#pragma unroll
        for (int c = 0; c < 4; ++c) {
            const int chunk = (wave << 2) | c;
            const int row   = (chunk << 3) | rowInChunk;
            const unsigned short* gA = A  + aBase + (long long)row * K + k0 + col8;
            const unsigned short* gB = Bw + bBase + (long long)row * K + k0 + col8;
            __builtin_amdgcn_global_load_lds(
                (const __attribute__((address_space(1))) unsigned int*)gA,
                (__attribute__((address_space(3))) unsigned int*)&ldsA[chunk * 512],
                16, 0, 0);
            __builtin_amdgcn_global_load_lds(
                (const __attribute__((address_space(1))) unsigned int*)gB,
                (__attribute__((address_space(3))) unsigned int*)&ldsB[chunk * 512],
                16, 0, 0);
        }
        __syncthreads();

#pragma unroll
        for (int kk = 0; kk < 2; ++kk) {
            bf16x8 av[4], bv[4];
#pragma unroll
            for (int i = 0; i < 4; ++i) {
                const int r    = waveM * 64 + i * 16 + row16;
                const int slot = (kk * 4 + quad) ^ sw;
                av[i] = *(const bf16x8*)&ldsA[r * BK + slot * 8];
            }
#pragma unroll
            for (int j = 0; j < 4; ++j) {
                const int r    = waveN * 64 + j * 16 + row16;
                const int slot = (kk * 4 + quad) ^ sw;
                bv[j] = *(const bf16x8*)&ldsB[r * BK + slot * 8];
            }
#pragma unroll
            for (int i = 0; i < 4; ++i)
#pragma unroll
                for (int j = 0; j < 4; ++j)
                    acc[i][j] = __builtin_amdgcn_mfma_f32_16x16x32_bf16(
                        av[i], bv[j], acc[i][j], 0, 0, 0);
        }
    }

    const int colBase = blockN0 + waveN * 64;
    const int rowBase = blockM0 + waveM * 64;
    float biasf[4];
#pragma unroll
    for (int j = 0; j < 4; ++j)
        biasf[j] = bias[colBase + j * 16 + row16];

#pragma unroll
    for (int i = 0; i < 4; ++i) {
        const int row0 = rowBase + i * 16 + quad * 4;
#pragma unroll
        for (int j = 0; j < 4; ++j) {
            const int col = colBase + j * 16 + row16;
#pragma unroll
            for (int r = 0; r < 4; ++r) {
                C[(long long)(row0 + r) * N + col] = acc[i][j][r] + biasf[j];
            }
        }
    }
}

// ---------------- fallback: fused kernel (no workspace) ---------------------
__global__ __launch_bounds__(256) void hqq_gemm_fused_f32(
    const float* __restrict__ A,
    const int*   __restrict__ Wq,
    const float* __restrict__ scale,
    const float* __restrict__ zero,
    const float* __restrict__ bias,
    float*       __restrict__ C,
    int M, int N, int K, int G, int GROUP)
{
    __shared__ unsigned short ldsA[BM * BK];
    __shared__ unsigned short ldsB[BN * BK];

    const int tid   = threadIdx.x;
    const int lane  = tid & 63;
    const int wave  = tid >> 6;
    const int waveM = wave >> 1;
    const int waveN = wave & 1;

    const int blockN0 = blockIdx.x * BN;
    const int blockM0 = blockIdx.y * BM;

    const int row16 = lane & 15;
    const int quad  = lane >> 4;

    f32x4 acc[4][4];
#pragma unroll
    for (int i = 0; i < 4; ++i)
#pragma unroll
        for (int j = 0; j < 4; ++j)
            acc[i][j] = (f32x4){0.f, 0.f, 0.f, 0.f};

    for (int k0 = 0; k0 < K; k0 += BK) {
        const int g = k0 / GROUP;
        int4 ra[4], rb[4];
#pragma unroll
        for (int c = 0; c < 4; ++c) {
            const int chunk = c * 256 + tid;
            const int row   = chunk >> 3;
            const int col   = (chunk & 7) * 8;

            const float* ap = A + (long long)(blockM0 + row) * K + k0 + col;
            const float4 a0 = *(const float4*)(ap);
            const float4 a1 = *(const float4*)(ap + 4);
            int4 da;
            da.x = pack_bf16x2(a0.x, a0.y);
            da.y = pack_bf16x2(a0.z, a0.w);
            da.z = pack_bf16x2(a1.x, a1.y);
            da.w = pack_bf16x2(a1.z, a1.w);
            ra[c] = da;

            const int n = blockN0 + row;
            const float s  = scale[(long long)n * G + g];
            const float z  = zero [(long long)n * G + g];
            const float mz = -z * s;
            const long long wb = (long long)n * K + k0 + col;
            const int4 q0 = *(const int4*)(Wq + wb);
            const int4 q1 = *(const int4*)(Wq + wb + 4);
            int4 db;
            db.x = pack_bf16x2((float)q0.x * s + mz, (float)q0.y * s + mz);
            db.y = pack_bf16x2((float)q0.z * s + mz, (float)q0.w * s + mz);
            db.z = pack_bf16x2((float)q1.x * s + mz, (float)q1.y * s + mz);
            db.w = pack_bf16x2((float)q1.z * s + mz, (float)q1.w * s + mz);
            rb[c] = db;
        }

        __syncthreads();
#pragma unroll
        for (int c = 0; c < 4; ++c) {
            const int chunk = c * 256 + tid;
            *(int4*)&ldsA[chunk * 8] = ra[c];
            *(int4*)&ldsB[chunk * 8] = rb[c];
        }
        __syncthreads();

#pragma unroll
        for (int kk = 0; kk < 2; ++kk) {
            const int kOff = kk * 32 + quad * 8;
            bf16x8 av[4], bv[4];
#pragma unroll
            for (int i = 0; i < 4; ++i)
                av[i] = *(const bf16x8*)&ldsA[(waveM * 64 + i * 16 + row16) * BK + kOff];
#pragma unroll
            for (int j = 0; j < 4; ++j)
                bv[j] = *(const bf16x8*)&ldsB[(waveN * 64 + j * 16 + row16) * BK + kOff];
#pragma unroll
            for (int i = 0; i < 4; ++i)
#pragma unroll
                for (int j = 0; j < 4; ++j)
                    acc[i][j] = __builtin_amdgcn_mfma_f32_16x16x32_bf16(
                        av[i], bv[j], acc[i][j], 0, 0, 0);
        }
    }

    const int colBase = blockN0 + waveN * 64;
    const int rowBase = blockM0 + waveM * 64;
    float biasf[4];
#pragma unroll
    for (int j = 0; j < 4; ++j)
        biasf[j] = bias[colBase + j * 16 + row16];

#pragma unroll
    for (int i = 0; i < 4; ++i) {
        const int row0 = rowBase + i * 16 + quad * 4;
#pragma unroll
        for (int j = 0; j < 4; ++j) {
            const int col = colBase + j * 16 + row16;
#pragma unroll
            for (int r = 0; r < 4; ++r) {
                C[(long long)(row0 + r) * N + col] = acc[i][j][r] + biasf[j];
            }
        }
    }
}

extern "C" void kernel_launch(void* const* d_in, const int* in_sizes, int n_in,
                              void* d_out, int out_size, void* d_ws, size_t ws_size,
                              hipStream_t stream) {
    (void)n_in; (void)out_size;

    const float* x     = (const float*)d_in[0];
    const int*   Wq    = (const int*)d_in[1];
    const float* scale = (const float*)d_in[2];
    const float* zero  = (const float*)d_in[3];
    const float* bias  = (const float*)d_in[4];
    float*       out   = (float*)d_out;

    const int N     = in_sizes[4];            // 4096
    const int G     = in_sizes[2] / N;        // 32
    const int K     = in_sizes[1] / N;        // 4096
    const int M     = in_sizes[0] / K;        // 4096 (B*S)
    const int GROUP = K / G;                  // 128

    const size_t needWs = (size_t)N * K * 2 + (size_t)M * K * 2;  // 64 MB

    if (ws_size >= needWs) {
        unsigned short* Wd = (unsigned short*)d_ws;                        // [N,K] bf16
        unsigned short* Ad = (unsigned short*)((char*)d_ws + (size_t)N * K * 2);  // [M,K] bf16

        const int aUnits = (int)((long long)M * K / 8);
        const int wUnits = (int)((long long)N * K / 8);
        prepass_kernel<<<2048, 256, 0, stream>>>(x, Ad, Wq, scale, zero, Wd,
                                                 aUnits, wUnits, K, G, GROUP);

        const int nwg = (N >> 8) * (M >> 8);
        if ((M % 256) == 0 && (N % 256) == 0 && (K % 128) == 0 && (nwg % 8) == 0) {
            gemm256_bf16_nt<<<nwg, 512, 0, stream>>>(Ad, Wd, bias, out, M, N, K);
        } else {
            dim3 grid(N / BN, M / BM);
            gemm_bf16_nt<<<grid, 256, 0, stream>>>(Ad, Wd, bias, out, M, N, K);
        }
    } else {
        dim3 grid(N / BN, M / BM);
        hqq_gemm_fused_f32<<<grid, 256, 0, stream>>>(x, Wq, scale, zero, bias, out,
                                                     M, N, K, G, GROUP);
    }
}

// Round 3
// 283.947 us; speedup vs baseline: 1.1328x; 1.1328x over previous
//
#include <hip/hip_runtime.h>
#include <hip/hip_bf16.h>

// HQQ 4-bit linear: out = x @ dequant(W_q)^T + bias
// M=B*S=4096, K=4096, N=4096, GROUP=128. Output FP32.
//
// Round 9: faithful 8-phase (4 phases/K-tile) 256x256 GEMM per the m201
// template. BK=64, 2-deep K-tile double buffer split into K-half subtiles
// (256x32, 16KB, 2 global_load_lds/thread). Per phase: {4-8 ds_read_b128,
// stage ONE half-tile, barrier, 16 MFMA in setprio(1)}. vmcnt(6) once per
// K-tile (3 half-tiles stay in flight across barriers - never drains in the
// main loop). Stream bookkeeping: issue runs 7 half-tile units ahead of
// consumption; vmcnt(6) at phase 4 retires exactly through the next tile's
// last unit. Swizzle/fragment math identical to round 8 (verified, 0 bank
// conflicts). Prepass unchanged.

typedef __bf16 bf16x8 __attribute__((ext_vector_type(8)));
typedef float f32x4 __attribute__((ext_vector_type(4)));

#define BM 128
#define BN 128
#define BK 64

static __device__ __forceinline__ int pack_bf16x2(float a, float b) {
    __hip_bfloat162 p = __float22bfloat162_rn(make_float2(a, b));
    int r;
    __builtin_memcpy(&r, &p, 4);
    return r;
}

// ---------------- fused pre-pass: convert x AND dequant Wq ------------------
__global__ __launch_bounds__(256) void prepass_kernel(
    const float* __restrict__ X, unsigned short* __restrict__ Ad,
    const int*   __restrict__ Wq,
    const float* __restrict__ scale,
    const float* __restrict__ zero,
    unsigned short* __restrict__ Wd,
    int aUnits, int wUnits, int K, int G, int GROUP)
{
    const int stride = gridDim.x * blockDim.x;
    const int t0     = blockIdx.x * blockDim.x + threadIdx.x;

    for (int u = t0; u < aUnits; u += stride) {
        const long long f = (long long)u * 8;
        const float4 a0 = *(const float4*)(X + f);
        const float4 a1 = *(const float4*)(X + f + 4);
        int4 d;
        d.x = pack_bf16x2(a0.x, a0.y);
        d.y = pack_bf16x2(a0.z, a0.w);
        d.z = pack_bf16x2(a1.x, a1.y);
        d.w = pack_bf16x2(a1.z, a1.w);
        *(int4*)(Ad + f) = d;
    }

    const int unitsPerRow = K >> 3;
    for (int u = t0; u < wUnits; u += stride) {
        const int n = u / unitsPerRow;
        const int k = (u - n * unitsPerRow) * 8;
        const int g = k / GROUP;
        const float s  = scale[(long long)n * G + g];
        const float z  = zero [(long long)n * G + g];
        const float mz = -z * s;

        const long long f = (long long)n * K + k;
        const int4 q0 = *(const int4*)(Wq + f);
        const int4 q1 = *(const int4*)(Wq + f + 4);
        int4 d;
        d.x = pack_bf16x2((float)q0.x * s + mz, (float)q0.y * s + mz);
        d.y = pack_bf16x2((float)q0.z * s + mz, (float)q0.w * s + mz);
        d.z = pack_bf16x2((float)q1.x * s + mz, (float)q1.y * s + mz);
        d.w = pack_bf16x2((float)q1.z * s + mz, (float)q1.w * s + mz);
        *(int4*)(Wd + f) = d;
    }
}

// ---------------- GEMM: 256x256 tile, 4-phase/K-tile pipeline ---------------
// 512 threads = 8 waves (2M x 4N); wave owns 128x64 of C = 8x4 fragments.
// LDS: [2 buf][2 khalf] subtiles of 256x32 bf16 (16KB each) per operand,
// 128 KiB total. Subtile packing (verified round 8): phys row R (0..127)
// holds logical rows 2R,2R+1 x 4 chunks of 8 bf16, slot j of row R maps to
// ju=j^(R&7): logical row 2R+(ju>>2), col chunk ju&3. Writers pre-swizzle
// the global source (global_load_lds is linear); readers XOR the same term.
__global__ __launch_bounds__(512, 2) void gemm256_8ph(
    const unsigned short* __restrict__ A,     // bf16 bits [M,K]
    const unsigned short* __restrict__ Bw,    // bf16 bits [N,K]
    const float* __restrict__ bias,           // fp32 [N]
    float*       __restrict__ C,              // fp32 [M,N]
    int M, int N, int K)
{
    __shared__ unsigned short ldsA[2][2][8192];   // [buf][kh][256x32 packed]
    __shared__ unsigned short ldsB[2][2][8192];

    const int tid  = threadIdx.x;
    const int lane = tid & 63;
    const int wave = tid >> 6;     // 0..7
    const int wm   = wave >> 2;    // 0..1  (M half)
    const int wn   = wave & 3;     // 0..3  (N quarter)

    // XCD-bijective swizzle (nwg % 8 == 0 guaranteed by launcher).
    const int nwg  = (N >> 8) * (M >> 8);
    const int cpx  = nwg >> 3;
    const int bid  = blockIdx.x;
    const int wgid = (bid & 7) * cpx + (bid >> 3);
    const int bx   = wgid % (N >> 8);
    const int by   = wgid / (N >> 8);
    const int blockN0 = bx << 8;
    const int blockM0 = by << 8;

    // staging source offsets per load l (pre-swizzled global; LDS linear)
    long long gSrcA[2], gSrcB[2];
    int ldsDst[2];
#pragma unroll
    for (int l = 0; l < 2; ++l) {
        const int s  = l * 512 + tid;
        const int R  = s >> 3;
        const int j  = s & 7;
        const int ju = j ^ (R & 7);
        const int r  = 2 * R + (ju >> 2);
        const int cc = ju & 3;
        gSrcA[l] = (long long)(blockM0 + r) * K + cc * 8;
        gSrcB[l] = (long long)(blockN0 + r) * K + cc * 8;
        ldsDst[l] = (l * 512 + wave * 64) * 8;   // wave-uniform elem base
    }

    // fragment read offsets (elements within a 16KB subtile)
    const int row16 = lane & 15;
    const int quad  = lane >> 4;
    int offA[8], offB[4];
#pragma unroll
    for (int m = 0; m < 8; ++m) {
        const int r = wm * 128 + m * 16 + row16;
        const int R = r >> 1;
        const int j = (((r & 1) << 2) | quad) ^ (R & 7);
        offA[m] = R * 64 + j * 8;
    }
#pragma unroll
    for (int n = 0; n < 4; ++n) {
        const int r = wn * 64 + n * 16 + row16;
        const int R = r >> 1;
        const int j = (((r & 1) << 2) | quad) ^ (R & 7);
        offB[n] = R * 64 + j * 8;
    }

    f32x4 acc[8][4];
#pragma unroll
    for (int m = 0; m < 8; ++m)
#pragma unroll
        for (int n = 0; n < 4; ++n)
            acc[m][n] = (f32x4){0.f, 0.f, 0.f, 0.f};

#define STAGE_A(T_, KH_)                                                      \
    do {                                                                      \
        const int b_ = (T_) & 1;                                              \
        const long long ko_ = (long long)(T_) * 64 + (KH_) * 32;              \
        __builtin_amdgcn_global_load_lds(                                     \
            (const __attribute__((address_space(1))) unsigned int*)           \
                (A + gSrcA[0] + ko_),                                         \
            (__attribute__((address_space(3))) unsigned int*)                 \
                (&ldsA[b_][KH_][ldsDst[0]]), 16, 0, 0);                       \
        __builtin_amdgcn_global_load_lds(                                     \
            (const __attribute__((address_space(1))) unsigned int*)           \
                (A + gSrcA[1] + ko_),                                         \
            (__attribute__((address_space(3))) unsigned int*)                 \
                (&ldsA[b_][KH_][ldsDst[1]]), 16, 0, 0);                       \
    } while (0)

#define STAGE_B(T_, KH_)                                                      \
    do {                                                                      \
        const int b_ = (T_) & 1;                                              \
        const long long ko_ = (long long)(T_) * 64 + (KH_) * 32;              \
        __builtin_amdgcn_global_load_lds(                                     \
            (const __attribute__((address_space(1))) unsigned int*)           \
                (Bw + gSrcB[0] + ko_),                                        \
            (__attribute__((address_space(3))) unsigned int*)                 \
                (&ldsB[b_][KH_][ldsDst[0]]), 16, 0, 0);                       \
        __builtin_amdgcn_global_load_lds(                                     \
            (const __attribute__((address_space(1))) unsigned int*)           \
                (Bw + gSrcB[1] + ko_),                                        \
            (__attribute__((address_space(3))) unsigned int*)                 \
                (&ldsB[b_][KH_][ldsDst[1]]), 16, 0, 0);                       \
    } while (0)

#define READ_BV(c_, kk_)                                                      \
    bv0 = *(const bf16x8*)&ldsB[c_][kk_][offB[0]];                            \
    bv1 = *(const bf16x8*)&ldsB[c_][kk_][offB[1]];                            \
    bv2 = *(const bf16x8*)&ldsB[c_][kk_][offB[2]];                            \
    bv3 = *(const bf16x8*)&ldsB[c_][kk_][offB[3]];

#define READ_AV(c_, kk_, mh_)                                                 \
    av0 = *(const bf16x8*)&ldsA[c_][kk_][offA[(mh_) * 4 + 0]];                \
    av1 = *(const bf16x8*)&ldsA[c_][kk_][offA[(mh_) * 4 + 1]];                \
    av2 = *(const bf16x8*)&ldsA[c_][kk_][offA[(mh_) * 4 + 2]];                \
    av3 = *(const bf16x8*)&ldsA[c_][kk_][offA[(mh_) * 4 + 3]];

#define MFROW(mi_, av_)                                                       \
    acc[mi_][0] = __builtin_amdgcn_mfma_f32_16x16x32_bf16(av_, bv0, acc[mi_][0], 0, 0, 0); \
    acc[mi_][1] = __builtin_amdgcn_mfma_f32_16x16x32_bf16(av_, bv1, acc[mi_][1], 0, 0, 0); \
    acc[mi_][2] = __builtin_amdgcn_mfma_f32_16x16x32_bf16(av_, bv2, acc[mi_][2], 0, 0, 0); \
    acc[mi_][3] = __builtin_amdgcn_mfma_f32_16x16x32_bf16(av_, bv3, acc[mi_][3], 0, 0, 0);

#define MFMA16(mh_)                                                           \
    __builtin_amdgcn_s_setprio(1);                                            \
    MFROW((mh_) * 4 + 0, av0);                                                \
    MFROW((mh_) * 4 + 1, av1);                                                \
    MFROW((mh_) * 4 + 2, av2);                                                \
    MFROW((mh_) * 4 + 3, av3);                                                \
    __builtin_amdgcn_s_setprio(0);

    const int NT = K >> 6;   // K-tiles of 64; NT=64 here

    // ---- prologue: stage 7 half-tile units (tile0 full + tile1 first 3) ----
    STAGE_A(0, 0); STAGE_B(0, 0); STAGE_A(0, 1); STAGE_B(0, 1);
    STAGE_A(1, 0); STAGE_B(1, 0); STAGE_A(1, 1);
    asm volatile("s_waitcnt vmcnt(6)" ::: "memory");   // tile0 resident
    __builtin_amdgcn_s_barrier();

    bf16x8 av0, av1, av2, av3, bv0, bv1, bv2, bv3;

    // ---- main loop: compute tile T, stage units 7 ahead of consumption ----
    // (T,P1)->B(T+1,kh1)  (T,P2)->A(T+2,kh0)  (T,P3)->B(T+2,kh0)
    // (T,P4)->A(T+2,kh1) + vmcnt(6): retires through B(T+1,kh1) ->
    // tile T+1 fully resident entering the next iteration.
#pragma unroll 2
    for (int T = 0; T <= NT - 3; ++T) {
        const int c = T & 1;
        // P1: m0-3 x kk0
        READ_BV(c, 0);
        READ_AV(c, 0, 0);
        STAGE_B(T + 1, 1);
        __builtin_amdgcn_s_barrier();
        MFMA16(0);
        // P2: m4-7 x kk0 (bv reused)
        READ_AV(c, 0, 1);
        STAGE_A(T + 2, 0);
        __builtin_amdgcn_s_barrier();
        MFMA16(1);
        // P3: m0-3 x kk1
        READ_BV(c, 1);
        READ_AV(c, 1, 0);
        STAGE_B(T + 2, 0);
        __builtin_amdgcn_s_barrier();
        MFMA16(0);
        // P4: m4-7 x kk1
        READ_AV(c, 1, 1);
        STAGE_A(T + 2, 1);
        asm volatile("s_waitcnt vmcnt(6)" ::: "memory");
        __builtin_amdgcn_s_barrier();
        MFMA16(1);
    }

    // ---- epilogue: last missing unit, drain, compute tiles NT-2, NT-1 ----
    STAGE_B(NT - 1, 1);
    asm volatile("s_waitcnt vmcnt(0)" ::: "memory");
    __builtin_amdgcn_s_barrier();
    {
        const int c = (NT - 2) & 1;
        READ_BV(c, 0); READ_AV(c, 0, 0); MFMA16(0);
        READ_AV(c, 0, 1); MFMA16(1);
        READ_BV(c, 1); READ_AV(c, 1, 0); MFMA16(0);
        READ_AV(c, 1, 1); MFMA16(1);
    }
    {
        const int c = (NT - 1) & 1;
        READ_BV(c, 0); READ_AV(c, 0, 0); MFMA16(0);
        READ_AV(c, 0, 1); MFMA16(1);
        READ_BV(c, 1); READ_AV(c, 1, 0); MFMA16(0);
        READ_AV(c, 1, 1); MFMA16(1);
    }

#undef STAGE_A
#undef STAGE_B
#undef READ_BV
#undef READ_AV
#undef MFROW
#undef MFMA16

    // ---- C write: layout col=lane&15, row=quad*4+reg [m89-verified] ----
    const int colBase = blockN0 + wn * 64;
    const int rowBase = blockM0 + wm * 128;
    float biasf[4];
#pragma unroll
    for (int n = 0; n < 4; ++n)
        biasf[n] = bias[colBase + n * 16 + row16];

#pragma unroll
    for (int m = 0; m < 8; ++m) {
        const int row0 = rowBase + m * 16 + quad * 4;
#pragma unroll
        for (int n = 0; n < 4; ++n) {
            const int col = colBase + n * 16 + row16;
#pragma unroll
            for (int r = 0; r < 4; ++r) {
                C[(long long)(row0 + r) * N + col] = acc[m][n][r] + biasf[n];
            }
        }
    }
}

// ---------------- legacy 128x128 GEMM (fallback for odd shapes) -------------
__global__ __launch_bounds__(256, 2) void gemm_bf16_nt(
    const unsigned short* __restrict__ A,
    const unsigned short* __restrict__ Bw,
    const float* __restrict__ bias,
    float*       __restrict__ C,
    int M, int N, int K)
{
    __shared__ unsigned short ldsA[BM * BK];
    __shared__ unsigned short ldsB[BN * BK];

    const int tid   = threadIdx.x;
    const int lane  = tid & 63;
    const int wave  = tid >> 6;
    const int waveM = wave >> 1;
    const int waveN = wave & 1;

    const int blockN0 = blockIdx.x * BN;
    const int blockM0 = blockIdx.y * BM;

    const long long aBase = (long long)blockM0 * K;
    const long long bBase = (long long)blockN0 * K;

    const int rowInChunk = lane >> 3;
    const int colChunkSw = (lane & 7) ^ rowInChunk;
    const int col8       = colChunkSw * 8;

    f32x4 acc[4][4];
#pragma unroll
    for (int i = 0; i < 4; ++i)
#pragma unroll
        for (int j = 0; j < 4; ++j)
            acc[i][j] = (f32x4){0.f, 0.f, 0.f, 0.f};

    const int row16 = lane & 15;
    const int quad  = lane >> 4;
    const int sw    = row16 & 7;

    for (int k0 = 0; k0 < K; k0 += BK) {
        __syncthreads();
#pragma unroll
        for (int c = 0; c < 4; ++c) {
            const int chunk = (wave << 2) | c;
            const int row   = (chunk << 3) | rowInChunk;
            const unsigned short* gA = A  + aBase + (long long)row * K + k0 + col8;
            const unsigned short* gB = Bw + bBase + (long long)row * K + k0 + col8;
            __builtin_amdgcn_global_load_lds(
                (const __attribute__((address_space(1))) unsigned int*)gA,
                (__attribute__((address_space(3))) unsigned int*)&ldsA[chunk * 512],
                16, 0, 0);
            __builtin_amdgcn_global_load_lds(
                (const __attribute__((address_space(1))) unsigned int*)gB,
                (__attribute__((address_space(3))) unsigned int*)&ldsB[chunk * 512],
                16, 0, 0);
        }
        __syncthreads();

#pragma unroll
        for (int kk = 0; kk < 2; ++kk) {
            bf16x8 av[4], bv[4];
#pragma unroll
            for (int i = 0; i < 4; ++i) {
                const int r    = waveM * 64 + i * 16 + row16;
                const int slot = (kk * 4 + quad) ^ sw;
                av[i] = *(const bf16x8*)&ldsA[r * BK + slot * 8];
            }
#pragma unroll
            for (int j = 0; j < 4; ++j) {
                const int r    = waveN * 64 + j * 16 + row16;
                const int slot = (kk * 4 + quad) ^ sw;
                bv[j] = *(const bf16x8*)&ldsB[r * BK + slot * 8];
            }
#pragma unroll
            for (int i = 0; i < 4; ++i)
#pragma unroll
                for (int j = 0; j < 4; ++j)
                    acc[i][j] = __builtin_amdgcn_mfma_f32_16x16x32_bf16(
                        av[i], bv[j], acc[i][j], 0, 0, 0);
        }
    }

    const int colBase = blockN0 + waveN * 64;
    const int rowBase = blockM0 + waveM * 64;
    float biasf[4];
#pragma unroll
    for (int j = 0; j < 4; ++j)
        biasf[j] = bias[colBase + j * 16 + row16];

#pragma unroll
    for (int i = 0; i < 4; ++i) {
        const int row0 = rowBase + i * 16 + quad * 4;
#pragma unroll
        for (int j = 0; j < 4; ++j) {
            const int col = colBase + j * 16 + row16;
#pragma unroll
            for (int r = 0; r < 4; ++r) {
                C[(long long)(row0 + r) * N + col] = acc[i][j][r] + biasf[j];
            }
        }
    }
}

// ---------------- fallback: fused kernel (no workspace) ---------------------
__global__ __launch_bounds__(256) void hqq_gemm_fused_f32(
    const float* __restrict__ A,
    const int*   __restrict__ Wq,
    const float* __restrict__ scale,
    const float* __restrict__ zero,
    const float* __restrict__ bias,
    float*       __restrict__ C,
    int M, int N, int K, int G, int GROUP)
{
    __shared__ unsigned short ldsA[BM * BK];
    __shared__ unsigned short ldsB[BN * BK];

    const int tid   = threadIdx.x;
    const int lane  = tid & 63;
    const int wave  = tid >> 6;
    const int waveM = wave >> 1;
    const int waveN = wave & 1;

    const int blockN0 = blockIdx.x * BN;
    const int blockM0 = blockIdx.y * BM;

    const int row16 = lane & 15;
    const int quad  = lane >> 4;

    f32x4 acc[4][4];
#pragma unroll
    for (int i = 0; i < 4; ++i)
#pragma unroll
        for (int j = 0; j < 4; ++j)
            acc[i][j] = (f32x4){0.f, 0.f, 0.f, 0.f};

    for (int k0 = 0; k0 < K; k0 += BK) {
        const int g = k0 / GROUP;
        int4 ra[4], rb[4];
#pragma unroll
        for (int c = 0; c < 4; ++c) {
            const int chunk = c * 256 + tid;
            const int row   = chunk >> 3;
            const int col   = (chunk & 7) * 8;

            const float* ap = A + (long long)(blockM0 + row) * K + k0 + col;
            const float4 a0 = *(const float4*)(ap);
            const float4 a1 = *(const float4*)(ap + 4);
            int4 da;
            da.x = pack_bf16x2(a0.x, a0.y);
            da.y = pack_bf16x2(a0.z, a0.w);
            da.z = pack_bf16x2(a1.x, a1.y);
            da.w = pack_bf16x2(a1.z, a1.w);
            ra[c] = da;

            const int n = blockN0 + row;
            const float s  = scale[(long long)n * G + g];
            const float z  = zero [(long long)n * G + g];
            const float mz = -z * s;
            const long long wb = (long long)n * K + k0 + col;
            const int4 q0 = *(const int4*)(Wq + wb);
            const int4 q1 = *(const int4*)(Wq + wb + 4);
            int4 db;
            db.x = pack_bf16x2((float)q0.x * s + mz, (float)q0.y * s + mz);
            db.y = pack_bf16x2((float)q0.z * s + mz, (float)q0.w * s + mz);
            db.z = pack_bf16x2((float)q1.x * s + mz, (float)q1.y * s + mz);
            db.w = pack_bf16x2((float)q1.z * s + mz, (float)q1.w * s + mz);
            rb[c] = db;
        }

        __syncthreads();
#pragma unroll
        for (int c = 0; c < 4; ++c) {
            const int chunk = c * 256 + tid;
            *(int4*)&ldsA[chunk * 8] = ra[c];
            *(int4*)&ldsB[chunk * 8] = rb[c];
        }
        __syncthreads();

#pragma unroll
        for (int kk = 0; kk < 2; ++kk) {
            const int kOff = kk * 32 + quad * 8;
            bf16x8 av[4], bv[4];
#pragma unroll
            for (int i = 0; i < 4; ++i)
                av[i] = *(const bf16x8*)&ldsA[(waveM * 64 + i * 16 + row16) * BK + kOff];
#pragma unroll
            for (int j = 0; j < 4; ++j)
                bv[j] = *(const bf16x8*)&ldsB[(waveN * 64 + j * 16 + row16) * BK + kOff];
#pragma unroll
            for (int i = 0; i < 4; ++i)
#pragma unroll
                for (int j = 0; j < 4; ++j)
                    acc[i][j] = __builtin_amdgcn_mfma_f32_16x16x32_bf16(
                        av[i], bv[j], acc[i][j], 0, 0, 0);
        }
    }

    const int colBase = blockN0 + waveN * 64;
    const int rowBase = blockM0 + waveM * 64;
    float biasf[4];
#pragma unroll
    for (int j = 0; j < 4; ++j)
        biasf[j] = bias[colBase + j * 16 + row16];

#pragma unroll
    for (int i = 0; i < 4; ++i) {
        const int row0 = rowBase + i * 16 + quad * 4;
#pragma unroll
        for (int j = 0; j < 4; ++j) {
            const int col = colBase + j * 16 + row16;
#pragma unroll
            for (int r = 0; r < 4; ++r) {
                C[(long long)(row0 + r) * N + col] = acc[i][j][r] + biasf[j];
            }
        }
    }
}

extern "C" void kernel_launch(void* const* d_in, const int* in_sizes, int n_in,
                              void* d_out, int out_size, void* d_ws, size_t ws_size,
                              hipStream_t stream) {
    (void)n_in; (void)out_size;

    const float* x     = (const float*)d_in[0];
    const int*   Wq    = (const int*)d_in[1];
    const float* scale = (const float*)d_in[2];
    const float* zero  = (const float*)d_in[3];
    const float* bias  = (const float*)d_in[4];
    float*       out   = (float*)d_out;

    const int N     = in_sizes[4];            // 4096
    const int G     = in_sizes[2] / N;        // 32
    const int K     = in_sizes[1] / N;        // 4096
    const int M     = in_sizes[0] / K;        // 4096 (B*S)
    const int GROUP = K / G;                  // 128

    const size_t needWs = (size_t)N * K * 2 + (size_t)M * K * 2;  // 64 MB

    if (ws_size >= needWs) {
        unsigned short* Wd = (unsigned short*)d_ws;                        // [N,K] bf16
        unsigned short* Ad = (unsigned short*)((char*)d_ws + (size_t)N * K * 2);  // [M,K] bf16

        const int aUnits = (int)((long long)M * K / 8);
        const int wUnits = (int)((long long)N * K / 8);
        prepass_kernel<<<2048, 256, 0, stream>>>(x, Ad, Wq, scale, zero, Wd,
                                                 aUnits, wUnits, K, G, GROUP);

        const int nwg = (N >> 8) * (M >> 8);
        const int NT  = K >> 6;
        if ((M % 256) == 0 && (N % 256) == 0 && (K % 64) == 0 && NT >= 4 &&
            (nwg % 8) == 0) {
            gemm256_8ph<<<nwg, 512, 0, stream>>>(Ad, Wd, bias, out, M, N, K);
        } else {
            dim3 grid(N / BN, M / BM);
            gemm_bf16_nt<<<grid, 256, 0, stream>>>(Ad, Wd, bias, out, M, N, K);
        }
    } else {
        dim3 grid(N / BN, M / BM);
        hqq_gemm_fused_f32<<<grid, 256, 0, stream>>>(x, Wq, scale, zero, bias, out,
                                                     M, N, K, G, GROUP);
    }
}